// Round 21
// baseline (4275.332 us; speedup 1.0000x reference)
//
#include <hip/hip_runtime.h>
#include <stdint.h>

#define D_MODEL 768
#define NHEAD 4
#define DHEAD 192
#define SEQ 1024
#define NLAYER 12
#define NTOK 4096
#define NVOCAB 50257

typedef __attribute__((ext_vector_type(4))) float f32x4;
typedef __attribute__((ext_vector_type(4))) int i32x4;
typedef __attribute__((ext_vector_type(4))) unsigned short u16x4;

__device__ __forceinline__ unsigned short f2bf(float f) {
  unsigned u = __builtin_bit_cast(unsigned, f);
  u += 0x7FFFu + ((u >> 16) & 1u);
  return (unsigned short)(u >> 16);
}

// async global->LDS, 16B per lane; lds base must be wave-uniform
#define GLDS(src, dst)                                                   \
  __builtin_amdgcn_global_load_lds(                                      \
      (const __attribute__((address_space(1))) void*)(src),              \
      (__attribute__((address_space(3))) void*)(dst), 16, 0, 0)

#define FENCE asm volatile("" ::: "memory")
#define BAR()                         \
  do {                                \
    FENCE;                            \
    __builtin_amdgcn_s_barrier();     \
    FENCE;                            \
  } while (0)

// ---------------- embedding ----------------
__global__ __launch_bounds__(256) void embed_kernel(
    const int* __restrict__ x, const float* __restrict__ tok,
    const float* __restrict__ pos, float* __restrict__ h) {
  int row = blockIdx.x;
  int t = row & (SEQ - 1);
  int id = x[row];
  const float* tp = tok + (long)id * D_MODEL;
  const float* pp = pos + (long)t * D_MODEL;
  float* hp = h + (long)row * D_MODEL;
  for (int j = threadIdx.x; j < D_MODEL; j += 256)
    hp[j] = tp[j] + pp[j];
}

// ---- LN body (256 threads, one row) ----
__device__ __forceinline__ void ln_body(
    const float* __restrict__ h, const float* __restrict__ sc,
    const float* __restrict__ sh, unsigned short* __restrict__ out, int row) {
  __shared__ float red[4];
  const float* x = h + (long)row * D_MODEL;
  int tid = threadIdx.x;
  float v0 = x[tid], v1 = x[tid + 256], v2 = x[tid + 512];
  float s = v0 + v1 + v2;
  for (int o = 32; o > 0; o >>= 1) s += __shfl_xor(s, o);
  if ((tid & 63) == 0) red[tid >> 6] = s;
  __syncthreads();
  float mean = (red[0] + red[1] + red[2] + red[3]) * (1.0f / D_MODEL);
  __syncthreads();
  float d0 = v0 - mean, d1 = v1 - mean, d2 = v2 - mean;
  float q = d0 * d0 + d1 * d1 + d2 * d2;
  for (int o = 32; o > 0; o >>= 1) q += __shfl_xor(q, o);
  if ((tid & 63) == 0) red[tid >> 6] = q;
  __syncthreads();
  float var = (red[0] + red[1] + red[2] + red[3]) * (1.0f / D_MODEL);
  float r = rsqrtf(var + 1e-5f);
  unsigned short* op = out + (long)row * D_MODEL;
  op[tid]       = f2bf(d0 * r * sc[tid]       + sh[tid]);
  op[tid + 256] = f2bf(d1 * r * sc[tid + 256] + sh[tid + 256]);
  op[tid + 512] = f2bf(d2 * r * sc[tid + 512] + sh[tid + 512]);
}

// ---------------- standalone layernorm ----------------
__global__ __launch_bounds__(256) void ln_kernel(
    const float* __restrict__ h, const float* __restrict__ sc,
    const float* __restrict__ sh, unsigned short* __restrict__ out) {
  ln_body(h, sc, sh, out, blockIdx.x);
}

// ---- weight-transpose tile body (f32 [K][N] -> bf16 [N][K], 32x32) ----
__device__ __forceinline__ void wtile_body(
    const float* __restrict__ src, unsigned short* __restrict__ dst,
    int K, int N, int n0, int k0) {
  __shared__ unsigned short tile[32][33];
  int tx = threadIdx.x & 31, ty = threadIdx.x >> 5;
  int n = n0 + tx; if (n >= N) n = N - 1;
  #pragma unroll
  for (int i = 0; i < 4; ++i) {
    int k = k0 + ty + i * 8;
    tile[ty + i * 8][tx] = f2bf(src[(long)k * N + n]);
  }
  __syncthreads();
  #pragma unroll
  for (int i = 0; i < 4; ++i) {
    int nn = n0 + ty + i * 8;
    if (nn < N) dst[(long)nn * K + k0 + tx] = tile[tx][ty + i * 8];
  }
}

// ------- merged: per-layer weight transposes + LN1 (one launch) -------
__global__ __launch_bounds__(256) void wtln_kernel(
    const float* __restrict__ qw, const float* __restrict__ fw,
    const float* __restrict__ pw, unsigned short* __restrict__ tq,
    unsigned short* __restrict__ tf, unsigned short* __restrict__ tp,
    const float* __restrict__ h, const float* __restrict__ sc,
    const float* __restrict__ sh, unsigned short* __restrict__ lnb) {
  int bid = blockIdx.x;
  if (bid >= 6336) {
    ln_body(h, sc, sh, lnb, bid - 6336);
    return;
  }
  const float* src; unsigned short* dst; int K, N, nb;
  if (bid < 1728)               { src = qw; dst = tq; K = 768;  N = 2304; nb = 72; }
  else if ((bid -= 1728) < 2304){ src = fw; dst = tf; K = 768;  N = 3072; nb = 96; }
  else { bid -= 2304;             src = pw; dst = tp; K = 3072; N = 768;  nb = 24; }
  wtile_body(src, dst, K, N, (bid % nb) * 32, (bid / nb) * 32);
}

// ------- merged: head weight transpose + final LN (one launch) -------
__global__ __launch_bounds__(256) void wthln_kernel(
    const float* __restrict__ w, unsigned short* __restrict__ wt,
    const float* __restrict__ h, const float* __restrict__ sc,
    const float* __restrict__ sh, unsigned short* __restrict__ lnb) {
  int bid = blockIdx.x;
  if (bid >= 37704) {
    ln_body(h, sc, sh, lnb, bid - 37704);
    return;
  }
  int nx = bid % 1571, ky = bid / 1571;
  wtile_body(w, wt, 768, 50257, nx * 32, ky * 32);
}

// ======================= 256x256 8-phase GEMM, BK=64 =======================
// (R6-verified; used for the head only)
template<int MODE>
__global__ __launch_bounds__(512, 2) void gemm256_kernel(
    const unsigned short* __restrict__ A,   // [M][K]
    const unsigned short* __restrict__ B,   // [N][K]
    const float* __restrict__ bias,
    void* __restrict__ Cv, int ldc,
    int M, int N, int K, int mb,
    unsigned short* __restrict__ vtp) {
  __shared__ __align__(16) unsigned short lds[2][2][2][128 * 64];

  int tid = threadIdx.x;
  int lane = tid & 63;
  int wid = tid >> 6;
  int wm = wid >> 2;
  int wn = wid & 3;

  int bid = blockIdx.x;
  int mpx = mb >> 3;
  int xcd = bid & 7;
  int c = bid >> 3;
  int m0 = (xcd * mpx + (c & (mpx - 1))) * 256;
  int n0 = (c / mpx) * 256;

  auto stageA = [&](int buf, int half, int kt) {
    const unsigned short* src = A + (long)(m0 + half * 128) * K + kt * 64;
    #pragma unroll
    for (int i = 0; i < 2; ++i) {
      int chunk = i * 8 + wid;
      int r = chunk * 8 + (lane >> 3);
      int cc = ((lane & 7) ^ (lane >> 3)) << 3;
      GLDS(src + (long)r * K + cc, &lds[buf][0][half][chunk * 512]);
    }
  };
  auto stageB = [&](int buf, int half, int kt) {
    #pragma unroll
    for (int i = 0; i < 2; ++i) {
      int chunk = i * 8 + wid;
      int r = chunk * 8 + (lane >> 3);
      int cc = ((lane & 7) ^ (lane >> 3)) << 3;
      int rg = n0 + half * 128 + r;
      if (rg >= N) rg = N - 1;
      GLDS(B + (long)rg * K + kt * 64 + cc, &lds[buf][1][half][chunk * 512]);
    }
  };

  auto lda_frag = [&](int buf, int f, int s) -> i32x4 {
    int r = wm * 64 + (f & 3) * 16 + (lane & 15);
    int kb = s * 64 + ((lane >> 4) << 4);
    int off = r * 128 + (kb ^ ((r & 7) << 4));
    return *(const i32x4*)((const char*)&lds[buf][0][f >> 2][0] + off);
  };
  auto ldb_frag = [&](int buf, int gg, int s) -> i32x4 {
    int r = wn * 32 + (gg & 1) * 16 + (lane & 15);
    int kb = s * 64 + ((lane >> 4) << 4);
    int off = r * 128 + (kb ^ ((r & 7) << 4));
    return *(const i32x4*)((const char*)&lds[buf][1][gg >> 1][0] + off);
  };

  f32x4 acc[8][4] = {};
  i32x4 a[4][2], b[4][2];

  int nt = K / 64;

  stageA(0, 0, 0); stageB(0, 0, 0); stageB(0, 1, 0); stageA(0, 1, 0);
  stageA(1, 0, 1); stageB(1, 0, 1); stageB(1, 1, 1);
  asm volatile("s_waitcnt vmcnt(6)" ::: "memory");
  BAR();

  for (int t = 0; t < nt; ++t) {
    int buf = t & 1, nbuf = buf ^ 1;
    #pragma unroll
    for (int fi = 0; fi < 4; ++fi) {
      a[fi][0] = lda_frag(buf, fi, 0);
      a[fi][1] = lda_frag(buf, fi, 1);
    }
    #pragma unroll
    for (int gi = 0; gi < 2; ++gi) {
      b[gi][0] = ldb_frag(buf, gi, 0);
      b[gi][1] = ldb_frag(buf, gi, 1);
    }
    if (t + 1 < nt) stageA(nbuf, 1, t + 1);
    BAR();
    __builtin_amdgcn_s_setprio(1);
    #pragma unroll
    for (int s = 0; s < 2; ++s)
      #pragma unroll
      for (int fi = 0; fi < 4; ++fi)
        #pragma unroll
        for (int gi = 0; gi < 2; ++gi)
          asm("v_mfma_f32_16x16x32_bf16 %0, %1, %2, %0"
              : "+v"(acc[fi][gi]) : "v"(b[gi][s]), "v"(a[fi][s]));
    __builtin_amdgcn_s_setprio(0);
    BAR();
    #pragma unroll
    for (int gi = 2; gi < 4; ++gi) {
      b[gi][0] = ldb_frag(buf, gi, 0);
      b[gi][1] = ldb_frag(buf, gi, 1);
    }
    if (t + 2 < nt) stageA(buf, 0, t + 2);
    BAR();
    __builtin_amdgcn_s_setprio(1);
    #pragma unroll
    for (int s = 0; s < 2; ++s)
      #pragma unroll
      for (int fi = 0; fi < 4; ++fi)
        #pragma unroll
        for (int gi = 2; gi < 4; ++gi)
          asm("v_mfma_f32_16x16x32_bf16 %0, %1, %2, %0"
              : "+v"(acc[fi][gi]) : "v"(b[gi][s]), "v"(a[fi][s]));
    __builtin_amdgcn_s_setprio(0);
    BAR();
    #pragma unroll
    for (int fi = 0; fi < 4; ++fi) {
      a[fi][0] = lda_frag(buf, 4 + fi, 0);
      a[fi][1] = lda_frag(buf, 4 + fi, 1);
    }
    if (t + 2 < nt) stageB(buf, 0, t + 2);
    BAR();
    __builtin_amdgcn_s_setprio(1);
    #pragma unroll
    for (int s = 0; s < 2; ++s)
      #pragma unroll
      for (int fi = 0; fi < 4; ++fi)
        #pragma unroll
        for (int gi = 2; gi < 4; ++gi)
          asm("v_mfma_f32_16x16x32_bf16 %0, %1, %2, %0"
              : "+v"(acc[4 + fi][gi]) : "v"(b[gi][s]), "v"(a[fi][s]));
    __builtin_amdgcn_s_setprio(0);
    BAR();
    if (t + 2 < nt) {
      stageB(buf, 1, t + 2);
      asm volatile("s_waitcnt vmcnt(6)" ::: "memory");
    } else if (t + 1 < nt) {
      asm volatile("s_waitcnt vmcnt(0)" ::: "memory");
    }
    BAR();
    __builtin_amdgcn_s_setprio(1);
    #pragma unroll
    for (int s = 0; s < 2; ++s)
      #pragma unroll
      for (int fi = 0; fi < 4; ++fi)
        #pragma unroll
        for (int gi = 0; gi < 2; ++gi)
          asm("v_mfma_f32_16x16x32_bf16 %0, %1, %2, %0"
              : "+v"(acc[4 + fi][gi]) : "v"(b[gi][s]), "v"(a[fi][s]));
    __builtin_amdgcn_s_setprio(0);
    BAR();
  }

  int cr = lane & 15;
  int cg = (lane >> 4) << 2;
  #pragma unroll
  for (int f = 0; f < 8; ++f) {
    long row = m0 + wm * 64 + (f & 3) * 16 + (f >> 2) * 128 + cr;
    #pragma unroll
    for (int gg = 0; gg < 4; ++gg) {
      int col = n0 + wn * 32 + (gg & 1) * 16 + (gg >> 1) * 128 + cg;
      f32x4 v = acc[f][gg];
      if (MODE == 0 || MODE == 1) {
        f32x4 bv = *(const f32x4*)(bias + col);
        u16x4 o;
        #pragma unroll
        for (int r = 0; r < 4; ++r) {
          float tt = v[r] + bv[r];
          if (MODE == 1) tt = fmaxf(tt, 0.f);
          o[r] = f2bf(tt);
        }
        *(u16x4*)((unsigned short*)Cv + row * (long)ldc + col) = o;
        if (MODE == 0 && vtp && col >= 1536) {
          int vcol = col - 1536;
          int hh = vcol / 192;
          int dh = vcol - hh * 192;
          int bb = (int)(row >> 10);
          int tt2 = (int)(row & 1023);
          unsigned short* vb =
              vtp + ((long)(bb * 4 + hh) * 192 + dh) * 1024 + tt2;
          #pragma unroll
          for (int r = 0; r < 4; ++r) vb[(long)r * 1024] = o[r];
        }
      } else {
        float* cp = (float*)Cv + row * (long)ldc + col;
        if (col + 4 <= N) {
          f32x4 bv = *(const f32x4*)(bias + col);
          f32x4 o;
          #pragma unroll
          for (int r = 0; r < 4; ++r) o[r] = v[r] + bv[r];
          *(f32x4*)cp = o;
        } else {
          #pragma unroll
          for (int r = 0; r < 4; ++r)
            if (col + r < N) cp[r] = v[r] + bias[col + r];
        }
      }
    }
  }
}

// ---------------- 128x128 GEMM (QKV / FC / S-exp / PV / PROJ) ----------------
// MODE 0: bf16 = acc + bias (+ fused V-transpose scatter if vtp)   (QKV)
// MODE 1: bf16 = relu(acc + bias)                                   (FC)
// MODE 6: P = bf16(exp(acc*alpha)) causal-masked + rowsum atomics   (S-exp)
// MODE 7: f32 += acc / rowsum[row]                                  (PV)
// MODE 3: f32 += acc + bias                                         (PROJ)
// MODE 8: split-K PROJ — blockIdx.y selects K-slice (K/gridDim.y);
//         f32 atomicAdd += acc (+ bias only from slice 0)
#define BM 128
#define BN 128
#define BKK 32

template<int MODE>
__global__ __launch_bounds__(256) void gemm_kernel(
    const unsigned short* __restrict__ A, int lda,
    const unsigned short* __restrict__ B, int ldb,
    const float* __restrict__ bias,
    void* __restrict__ Cv, int ldc,
    int M, int N, int K,
    int NI, long sAo, long sAi, long sBo, long sBi,
    long sCo, long sCi, float alpha, int causal, int mblocks,
    float* __restrict__ rowsum, unsigned short* __restrict__ vtp) {
  __shared__ __align__(16) unsigned short As[2][BM * BKK];
  __shared__ __align__(16) unsigned short Bs[2][BN * BKK];
  int z = blockIdx.z;
  int zo = z / NI, zi = z - zo * NI;
  A += zo * sAo + zi * sAi;
  B += zo * sBo + zi * sBi;
  long coff = zo * sCo + zi * sCi;

  int m0, n0;
  if (mblocks > 0) {
    int bid = blockIdx.x;
    int mpx = mblocks >> 3;
    int xcd = bid & 7;
    int c = bid >> 3;
    m0 = (xcd * mpx + (c & (mpx - 1))) * BM;
    n0 = (c / mpx) * BN;
  } else {
    m0 = blockIdx.y * BM;
    n0 = blockIdx.x * BN;
  }
  if (causal == 1 && n0 > m0 + BM - 1) return;
  int kmax;
  if (MODE == 8) {
    int ksl = K / (int)gridDim.y;          // K-slice per y-block
    A += (long)blockIdx.y * ksl;
    B += (long)blockIdx.y * ksl;
    kmax = ksl;
  } else {
    kmax = (causal == 2) ? min(K, m0 + BM) : K;
  }

  int tid = threadIdx.x;
  int lane = tid & 63;
  int wave = tid >> 6;
  int wm = (wave >> 1) * 64;
  int wn = (wave & 1) * 64;

  auto stage = [&](int buf, int k0) {
    #pragma unroll
    for (int i = 0; i < 2; ++i) {
      int c0 = i * 256 + wave * 64;
      int cc = c0 + lane;
      int row = cc >> 2;
      int ko = (cc & 3) << 3;
      GLDS(A + (long)(m0 + row) * lda + k0 + ko, As[buf] + c0 * 8);
      int rg = n0 + row; if (rg >= N) rg = N - 1;
      GLDS(B + (long)rg * ldb + k0 + ko, Bs[buf] + c0 * 8);
    }
  };

  f32x4 acc[4][4] = {};
  int nt = kmax / BKK;
  stage(0, 0);
  __syncthreads();
  int cur = 0;
  for (int t = 0; t < nt; ++t) {
    if (t + 1 < nt) stage(cur ^ 1, (t + 1) * BKK);
    int lr = lane & 15;
    int kg = (lane >> 4) << 3;
    i32x4 af[4], bf[4];
    #pragma unroll
    for (int mi = 0; mi < 4; ++mi)
      af[mi] = *(const i32x4*)(As[cur] + (wm + mi * 16 + lr) * BKK + kg);
    #pragma unroll
    for (int ni = 0; ni < 4; ++ni)
      bf[ni] = *(const i32x4*)(Bs[cur] + (wn + ni * 16 + lr) * BKK + kg);
    #pragma unroll
    for (int mi = 0; mi < 4; ++mi)
      #pragma unroll
      for (int ni = 0; ni < 4; ++ni)
        asm("v_mfma_f32_16x16x32_bf16 %0, %1, %2, %0"
            : "+v"(acc[mi][ni]) : "v"(bf[ni]), "v"(af[mi]));
    __syncthreads();
    cur ^= 1;
  }

  int cm = lane & 15;
  int cg = (lane >> 4) << 2;
  #pragma unroll
  for (int mi = 0; mi < 4; ++mi) {
    long row = m0 + wm + mi * 16 + cm;
    float rs = 0.f;
    #pragma unroll
    for (int ni = 0; ni < 4; ++ni) {
      int col = n0 + wn + ni * 16 + cg;
      f32x4 v = acc[mi][ni];
      if (MODE == 0 || MODE == 1) {           // N multiple of 128, no tail
        f32x4 bv = *(const f32x4*)(bias + col);
        u16x4 o;
        #pragma unroll
        for (int r = 0; r < 4; ++r) {
          float tt = v[r] + bv[r];
          if (MODE == 1) tt = fmaxf(tt, 0.f);
          o[r] = f2bf(tt);
        }
        *(u16x4*)((unsigned short*)Cv + coff + row * (long)ldc + col) = o;
        if (MODE == 0 && vtp && col >= 1536) {
          int vcol = col - 1536;
          int hh = vcol / 192;
          int dh = vcol - hh * 192;
          int bb = (int)(row >> 10);
          int tt2 = (int)(row & 1023);
          unsigned short* vb =
              vtp + ((long)(bb * 4 + hh) * 192 + dh) * 1024 + tt2;
          #pragma unroll
          for (int r = 0; r < 4; ++r) vb[(long)r * 1024] = o[r];
        }
      } else if (MODE == 6) {                 // exp-epilogue S->P (N=1024)
        u16x4 o;
        #pragma unroll
        for (int r = 0; r < 4; ++r) {
          float e = (col + r <= (int)row) ? __expf(v[r] * alpha) : 0.f;
          rs += e;
          o[r] = f2bf(e);
        }
        *(u16x4*)((unsigned short*)Cv + coff + row * (long)ldc + col) = o;
      } else if (MODE == 7) {                 // PV with fused normalize
        float inv = 1.0f / rowsum[(long)blockIdx.z * SEQ + row];
        float* cp = (float*)Cv + coff + row * (long)ldc + col;
        if (col + 4 <= N) {
          f32x4 old = *(f32x4*)cp;
          #pragma unroll
          for (int r = 0; r < 4; ++r) old[r] += v[r] * inv;
          *(f32x4*)cp = old;
        } else {
          #pragma unroll
          for (int r = 0; r < 4; ++r)
            if (col + r < N) cp[r] += v[r] * inv;
        }
      } else if (MODE == 8) {                 // split-K PROJ: atomic +=
        float* cp = (float*)Cv + coff + row * (long)ldc + col;
        #pragma unroll
        for (int r = 0; r < 4; ++r) {
          float bvr = (blockIdx.y == 0 && bias) ? bias[col + r] : 0.f;
          atomicAdd(cp + r, v[r] + bvr);
        }
      } else {                                // MODE 3
        float* cp = (float*)Cv + coff + row * (long)ldc + col;
        if (col + 4 <= N) {
          f32x4 bv = bias ? *(const f32x4*)(bias + col)
                          : f32x4{0.f, 0.f, 0.f, 0.f};
          f32x4 old = *(f32x4*)cp;
          #pragma unroll
          for (int r = 0; r < 4; ++r) old[r] += v[r] + bv[r];
          *(f32x4*)cp = old;
        } else {
          #pragma unroll
          for (int r = 0; r < 4; ++r) {
            if (col + r < N) {
              float bvr = bias ? bias[col + r] : 0.f;
              cp[r] += v[r] + bvr;
            }
          }
        }
      }
    }
    if (MODE == 6)
      atomicAdd(rowsum + (long)blockIdx.z * SEQ + row, rs);
  }
}

extern "C" void kernel_launch(void* const* d_in, const int* in_sizes, int n_in,
                              void* d_out, int out_size, void* d_ws, size_t ws_size,
                              hipStream_t stream) {
  const int*   x       = (const int*)  d_in[0];
  const float* tok_emb = (const float*)d_in[1];
  const float* pos_emb = (const float*)d_in[2];
  const float* ln1_s   = (const float*)d_in[3];
  const float* ln1_b   = (const float*)d_in[4];
  const float* qkv_w   = (const float*)d_in[5];
  const float* qkv_b   = (const float*)d_in[6];
  const float* ln2_s   = (const float*)d_in[7];
  const float* ln2_b   = (const float*)d_in[8];
  const float* fc_w    = (const float*)d_in[9];
  const float* fc_b    = (const float*)d_in[10];
  const float* proj_w  = (const float*)d_in[11];
  const float* proj_b  = (const float*)d_in[12];
  const float* lnf_s   = (const float*)d_in[13];
  const float* lnf_b   = (const float*)d_in[14];
  const float* head_w  = (const float*)d_in[15];
  const float* head_b  = (const float*)d_in[16];

  char* ws = (char*)d_ws;
  size_t off = 0;
  auto alloc = [&](size_t bytes) {
    char* p = ws + off;
    off += (bytes + 255) & ~(size_t)255;
    return p;
  };
  float*          h   = (float*)         alloc((size_t)NTOK * D_MODEL * 4);
  unsigned short* lnb = (unsigned short*)alloc((size_t)NTOK * D_MODEL * 2);
  unsigned short* qkv = (unsigned short*)alloc((size_t)NTOK * 2304 * 2);
  unsigned short* vt  = (unsigned short*)alloc((size_t)16 * DHEAD * SEQ * 2);
  unsigned short* mid = (unsigned short*)alloc((size_t)NTOK * 3072 * 2);
  unsigned short* P   = (unsigned short*)alloc((size_t)16 * SEQ * SEQ * 2);
  float*          rsm = (float*)         alloc((size_t)NLAYER * 16 * SEQ * 4);
  unsigned short* wtq = (unsigned short*)alloc((size_t)2304 * 768 * 2);
  unsigned short* wtf = (unsigned short*)alloc((size_t)3072 * 768 * 2);
  unsigned short* wtp = (unsigned short*)alloc((size_t)768 * 3072 * 2);
  unsigned short* wth = (unsigned short*)alloc((size_t)50304 * 768 * 2);

  // zero all per-layer rowsum slices once (graph-safe async memset)
  hipMemsetAsync(rsm, 0, (size_t)NLAYER * 16 * SEQ * 4, stream);

  embed_kernel<<<NTOK, 256, 0, stream>>>(x, tok_emb, pos_emb, h);

  const float rscale = 0.07216878364870323f;  // 1/sqrt(192)

  for (int l = 0; l < NLAYER; ++l) {
    float* rowsum = rsm + (long)l * 16 * SEQ;
    // merged weight transposes + LN1 (one launch)
    wtln_kernel<<<6336 + NTOK, 256, 0, stream>>>(
        qkv_w + (long)l * 768 * 2304, fc_w + (long)l * 768 * 3072,
        proj_w + (long)l * 3072 * 768, wtq, wtf, wtp,
        h, ln1_s + l * 768, ln1_b + l * 768, lnb);
    // ---- attention ----
    // QKV on 128^2 kernel (576 blocks) with fused V-transpose
    gemm_kernel<0><<<576, 256, 0, stream>>>(
        lnb, 768, wtq, 768, qkv_b + l * 2304, qkv, 2304,
        4096, 2304, 768, 1, 0, 0, 0, 0, 0, 0, 1.0f, 0, 32, nullptr, vt);
    // P = exp(scale * Q K^T) masked, rowsum accumulated
    gemm_kernel<6><<<dim3(8, 8, 16), 256, 0, stream>>>(
        qkv, 2304, qkv + 768, 2304, nullptr, P, 1024,
        1024, 1024, 192, 4,
        (long)1024 * 2304, 192, (long)1024 * 2304, 192,
        (long)4 * 1024 * 1024, (long)1024 * 1024, rscale, 1, 0, rowsum, nullptr);
    // h += (P / rowsum) V
    gemm_kernel<7><<<dim3(2, 8, 16), 256, 0, stream>>>(
        P, 1024, vt, 1024, nullptr, h, 768,
        1024, 192, 1024, 4,
        (long)4 * 1024 * 1024, (long)1024 * 1024,
        (long)4 * 192 * 1024, (long)192 * 1024,
        (long)1024 * 768, 192, 1.0f, 2, 0, rowsum, nullptr);
    // ---- MLP ----
    ln_kernel<<<NTOK, 256, 0, stream>>>(h, ln2_s + l * 768, ln2_b + l * 768, lnb);
    // FC on 128^2 kernel (768 blocks)
    gemm_kernel<1><<<768, 256, 0, stream>>>(
        lnb, 768, wtf, 768, fc_b + l * 3072, mid, 3072,
        4096, 3072, 768, 1, 0, 0, 0, 0, 0, 0, 1.0f, 0, 32, nullptr, nullptr);
    // PROJ split-K x4 (768 blocks total, atomicAdd into h)
    gemm_kernel<8><<<dim3(192, 4, 1), 256, 0, stream>>>(
        mid, 3072, wtp, 3072, proj_b + l * 768, h, 768,
        4096, 768, 3072, 1, 0, 0, 0, 0, 0, 0, 1.0f, 0, 32, nullptr, nullptr);
  }

  // ---- merged head weight transpose + final LN, then head GEMM ----
  wthln_kernel<<<1571 * 24 + NTOK, 256, 0, stream>>>(
      head_w, wth, h, lnf_s, lnf_b, lnb);
  gemm256_kernel<4><<<16 * 197, 512, 0, stream>>>(
      lnb, wth, head_b, (float*)d_out, 50257, 4096, 50257, 768, 16, nullptr);
}

// Round 22
// 2939.398 us; speedup vs baseline: 1.4545x; 1.4545x over previous
//
#include <hip/hip_runtime.h>
#include <stdint.h>

#define D_MODEL 768
#define NHEAD 4
#define DHEAD 192
#define SEQ 1024
#define NLAYER 12
#define NTOK 4096
#define NVOCAB 50257

typedef __attribute__((ext_vector_type(4))) float f32x4;
typedef __attribute__((ext_vector_type(4))) int i32x4;
typedef __attribute__((ext_vector_type(4))) unsigned short u16x4;

__device__ __forceinline__ unsigned short f2bf(float f) {
  unsigned u = __builtin_bit_cast(unsigned, f);
  u += 0x7FFFu + ((u >> 16) & 1u);
  return (unsigned short)(u >> 16);
}

// async global->LDS, 16B per lane; lds base must be wave-uniform
#define GLDS(src, dst)                                                   \
  __builtin_amdgcn_global_load_lds(                                      \
      (const __attribute__((address_space(1))) void*)(src),              \
      (__attribute__((address_space(3))) void*)(dst), 16, 0, 0)

#define FENCE asm volatile("" ::: "memory")
#define BAR()                         \
  do {                                \
    FENCE;                            \
    __builtin_amdgcn_s_barrier();     \
    FENCE;                            \
  } while (0)

// ---------------- embedding ----------------
__global__ __launch_bounds__(256) void embed_kernel(
    const int* __restrict__ x, const float* __restrict__ tok,
    const float* __restrict__ pos, float* __restrict__ h) {
  int row = blockIdx.x;
  int t = row & (SEQ - 1);
  int id = x[row];
  const float* tp = tok + (long)id * D_MODEL;
  const float* pp = pos + (long)t * D_MODEL;
  float* hp = h + (long)row * D_MODEL;
  for (int j = threadIdx.x; j < D_MODEL; j += 256)
    hp[j] = tp[j] + pp[j];
}

// ---- LN body (256 threads, one row) ----
__device__ __forceinline__ void ln_body(
    const float* __restrict__ h, const float* __restrict__ sc,
    const float* __restrict__ sh, unsigned short* __restrict__ out, int row) {
  __shared__ float red[4];
  const float* x = h + (long)row * D_MODEL;
  int tid = threadIdx.x;
  float v0 = x[tid], v1 = x[tid + 256], v2 = x[tid + 512];
  float s = v0 + v1 + v2;
  for (int o = 32; o > 0; o >>= 1) s += __shfl_xor(s, o);
  if ((tid & 63) == 0) red[tid >> 6] = s;
  __syncthreads();
  float mean = (red[0] + red[1] + red[2] + red[3]) * (1.0f / D_MODEL);
  __syncthreads();
  float d0 = v0 - mean, d1 = v1 - mean, d2 = v2 - mean;
  float q = d0 * d0 + d1 * d1 + d2 * d2;
  for (int o = 32; o > 0; o >>= 1) q += __shfl_xor(q, o);
  if ((tid & 63) == 0) red[tid >> 6] = q;
  __syncthreads();
  float var = (red[0] + red[1] + red[2] + red[3]) * (1.0f / D_MODEL);
  float r = rsqrtf(var + 1e-5f);
  unsigned short* op = out + (long)row * D_MODEL;
  op[tid]       = f2bf(d0 * r * sc[tid]       + sh[tid]);
  op[tid + 256] = f2bf(d1 * r * sc[tid + 256] + sh[tid + 256]);
  op[tid + 512] = f2bf(d2 * r * sc[tid + 512] + sh[tid + 512]);
}

// ---------------- standalone layernorm ----------------
__global__ __launch_bounds__(256) void ln_kernel(
    const float* __restrict__ h, const float* __restrict__ sc,
    const float* __restrict__ sh, unsigned short* __restrict__ out) {
  ln_body(h, sc, sh, out, blockIdx.x);
}

// ---- weight-transpose tile body (f32 [K][N] -> bf16 [N][K], 32x32) ----
__device__ __forceinline__ void wtile_body(
    const float* __restrict__ src, unsigned short* __restrict__ dst,
    int K, int N, int n0, int k0) {
  __shared__ unsigned short tile[32][33];
  int tx = threadIdx.x & 31, ty = threadIdx.x >> 5;
  int n = n0 + tx; if (n >= N) n = N - 1;
  #pragma unroll
  for (int i = 0; i < 4; ++i) {
    int k = k0 + ty + i * 8;
    tile[ty + i * 8][tx] = f2bf(src[(long)k * N + n]);
  }
  __syncthreads();
  #pragma unroll
  for (int i = 0; i < 4; ++i) {
    int nn = n0 + ty + i * 8;
    if (nn < N) dst[(long)nn * K + k0 + tx] = tile[tx][ty + i * 8];
  }
}

// ------- merged: per-layer weight transposes + LN1 (one launch) -------
__global__ __launch_bounds__(256) void wtln_kernel(
    const float* __restrict__ qw, const float* __restrict__ fw,
    const float* __restrict__ pw, unsigned short* __restrict__ tq,
    unsigned short* __restrict__ tf, unsigned short* __restrict__ tp,
    const float* __restrict__ h, const float* __restrict__ sc,
    const float* __restrict__ sh, unsigned short* __restrict__ lnb) {
  int bid = blockIdx.x;
  if (bid >= 6336) {
    ln_body(h, sc, sh, lnb, bid - 6336);
    return;
  }
  const float* src; unsigned short* dst; int K, N, nb;
  if (bid < 1728)               { src = qw; dst = tq; K = 768;  N = 2304; nb = 72; }
  else if ((bid -= 1728) < 2304){ src = fw; dst = tf; K = 768;  N = 3072; nb = 96; }
  else { bid -= 2304;             src = pw; dst = tp; K = 3072; N = 768;  nb = 24; }
  wtile_body(src, dst, K, N, (bid % nb) * 32, (bid / nb) * 32);
}

// ------- merged: head weight transpose + final LN (one launch) -------
__global__ __launch_bounds__(256) void wthln_kernel(
    const float* __restrict__ w, unsigned short* __restrict__ wt,
    const float* __restrict__ h, const float* __restrict__ sc,
    const float* __restrict__ sh, unsigned short* __restrict__ lnb) {
  int bid = blockIdx.x;
  if (bid >= 37704) {
    ln_body(h, sc, sh, lnb, bid - 37704);
    return;
  }
  int nx = bid % 1571, ky = bid / 1571;
  wtile_body(w, wt, 768, 50257, nx * 32, ky * 32);
}

// ======================= 256x256 8-phase GEMM, BK=64 =======================
// (R6-verified; used for the head only)
template<int MODE>
__global__ __launch_bounds__(512, 2) void gemm256_kernel(
    const unsigned short* __restrict__ A,   // [M][K]
    const unsigned short* __restrict__ B,   // [N][K]
    const float* __restrict__ bias,
    void* __restrict__ Cv, int ldc,
    int M, int N, int K, int mb,
    unsigned short* __restrict__ vtp) {
  __shared__ __align__(16) unsigned short lds[2][2][2][128 * 64];

  int tid = threadIdx.x;
  int lane = tid & 63;
  int wid = tid >> 6;
  int wm = wid >> 2;
  int wn = wid & 3;

  int bid = blockIdx.x;
  int mpx = mb >> 3;
  int xcd = bid & 7;
  int c = bid >> 3;
  int m0 = (xcd * mpx + (c & (mpx - 1))) * 256;
  int n0 = (c / mpx) * 256;

  auto stageA = [&](int buf, int half, int kt) {
    const unsigned short* src = A + (long)(m0 + half * 128) * K + kt * 64;
    #pragma unroll
    for (int i = 0; i < 2; ++i) {
      int chunk = i * 8 + wid;
      int r = chunk * 8 + (lane >> 3);
      int cc = ((lane & 7) ^ (lane >> 3)) << 3;
      GLDS(src + (long)r * K + cc, &lds[buf][0][half][chunk * 512]);
    }
  };
  auto stageB = [&](int buf, int half, int kt) {
    #pragma unroll
    for (int i = 0; i < 2; ++i) {
      int chunk = i * 8 + wid;
      int r = chunk * 8 + (lane >> 3);
      int cc = ((lane & 7) ^ (lane >> 3)) << 3;
      int rg = n0 + half * 128 + r;
      if (rg >= N) rg = N - 1;
      GLDS(B + (long)rg * K + kt * 64 + cc, &lds[buf][1][half][chunk * 512]);
    }
  };

  auto lda_frag = [&](int buf, int f, int s) -> i32x4 {
    int r = wm * 64 + (f & 3) * 16 + (lane & 15);
    int kb = s * 64 + ((lane >> 4) << 4);
    int off = r * 128 + (kb ^ ((r & 7) << 4));
    return *(const i32x4*)((const char*)&lds[buf][0][f >> 2][0] + off);
  };
  auto ldb_frag = [&](int buf, int gg, int s) -> i32x4 {
    int r = wn * 32 + (gg & 1) * 16 + (lane & 15);
    int kb = s * 64 + ((lane >> 4) << 4);
    int off = r * 128 + (kb ^ ((r & 7) << 4));
    return *(const i32x4*)((const char*)&lds[buf][1][gg >> 1][0] + off);
  };

  f32x4 acc[8][4] = {};
  i32x4 a[4][2], b[4][2];

  int nt = K / 64;

  stageA(0, 0, 0); stageB(0, 0, 0); stageB(0, 1, 0); stageA(0, 1, 0);
  stageA(1, 0, 1); stageB(1, 0, 1); stageB(1, 1, 1);
  asm volatile("s_waitcnt vmcnt(6)" ::: "memory");
  BAR();

  for (int t = 0; t < nt; ++t) {
    int buf = t & 1, nbuf = buf ^ 1;
    #pragma unroll
    for (int fi = 0; fi < 4; ++fi) {
      a[fi][0] = lda_frag(buf, fi, 0);
      a[fi][1] = lda_frag(buf, fi, 1);
    }
    #pragma unroll
    for (int gi = 0; gi < 2; ++gi) {
      b[gi][0] = ldb_frag(buf, gi, 0);
      b[gi][1] = ldb_frag(buf, gi, 1);
    }
    if (t + 1 < nt) stageA(nbuf, 1, t + 1);
    BAR();
    __builtin_amdgcn_s_setprio(1);
    #pragma unroll
    for (int s = 0; s < 2; ++s)
      #pragma unroll
      for (int fi = 0; fi < 4; ++fi)
        #pragma unroll
        for (int gi = 0; gi < 2; ++gi)
          asm("v_mfma_f32_16x16x32_bf16 %0, %1, %2, %0"
              : "+v"(acc[fi][gi]) : "v"(b[gi][s]), "v"(a[fi][s]));
    __builtin_amdgcn_s_setprio(0);
    BAR();
    #pragma unroll
    for (int gi = 2; gi < 4; ++gi) {
      b[gi][0] = ldb_frag(buf, gi, 0);
      b[gi][1] = ldb_frag(buf, gi, 1);
    }
    if (t + 2 < nt) stageA(buf, 0, t + 2);
    BAR();
    __builtin_amdgcn_s_setprio(1);
    #pragma unroll
    for (int s = 0; s < 2; ++s)
      #pragma unroll
      for (int fi = 0; fi < 4; ++fi)
        #pragma unroll
        for (int gi = 2; gi < 4; ++gi)
          asm("v_mfma_f32_16x16x32_bf16 %0, %1, %2, %0"
              : "+v"(acc[fi][gi]) : "v"(b[gi][s]), "v"(a[fi][s]));
    __builtin_amdgcn_s_setprio(0);
    BAR();
    #pragma unroll
    for (int fi = 0; fi < 4; ++fi) {
      a[fi][0] = lda_frag(buf, 4 + fi, 0);
      a[fi][1] = lda_frag(buf, 4 + fi, 1);
    }
    if (t + 2 < nt) stageB(buf, 0, t + 2);
    BAR();
    __builtin_amdgcn_s_setprio(1);
    #pragma unroll
    for (int s = 0; s < 2; ++s)
      #pragma unroll
      for (int fi = 0; fi < 4; ++fi)
        #pragma unroll
        for (int gi = 2; gi < 4; ++gi)
          asm("v_mfma_f32_16x16x32_bf16 %0, %1, %2, %0"
              : "+v"(acc[4 + fi][gi]) : "v"(b[gi][s]), "v"(a[fi][s]));
    __builtin_amdgcn_s_setprio(0);
    BAR();
    if (t + 2 < nt) {
      stageB(buf, 1, t + 2);
      asm volatile("s_waitcnt vmcnt(6)" ::: "memory");
    } else if (t + 1 < nt) {
      asm volatile("s_waitcnt vmcnt(0)" ::: "memory");
    }
    BAR();
    __builtin_amdgcn_s_setprio(1);
    #pragma unroll
    for (int s = 0; s < 2; ++s)
      #pragma unroll
      for (int fi = 0; fi < 4; ++fi)
        #pragma unroll
        for (int gi = 0; gi < 2; ++gi)
          asm("v_mfma_f32_16x16x32_bf16 %0, %1, %2, %0"
              : "+v"(acc[4 + fi][gi]) : "v"(b[gi][s]), "v"(a[fi][s]));
    __builtin_amdgcn_s_setprio(0);
    BAR();
  }

  int cr = lane & 15;
  int cg = (lane >> 4) << 2;
  #pragma unroll
  for (int f = 0; f < 8; ++f) {
    long row = m0 + wm * 64 + (f & 3) * 16 + (f >> 2) * 128 + cr;
    #pragma unroll
    for (int gg = 0; gg < 4; ++gg) {
      int col = n0 + wn * 32 + (gg & 1) * 16 + (gg >> 1) * 128 + cg;
      f32x4 v = acc[f][gg];
      if (MODE == 0 || MODE == 1) {
        f32x4 bv = *(const f32x4*)(bias + col);
        u16x4 o;
        #pragma unroll
        for (int r = 0; r < 4; ++r) {
          float tt = v[r] + bv[r];
          if (MODE == 1) tt = fmaxf(tt, 0.f);
          o[r] = f2bf(tt);
        }
        *(u16x4*)((unsigned short*)Cv + row * (long)ldc + col) = o;
        if (MODE == 0 && vtp && col >= 1536) {
          int vcol = col - 1536;
          int hh = vcol / 192;
          int dh = vcol - hh * 192;
          int bb = (int)(row >> 10);
          int tt2 = (int)(row & 1023);
          unsigned short* vb =
              vtp + ((long)(bb * 4 + hh) * 192 + dh) * 1024 + tt2;
          #pragma unroll
          for (int r = 0; r < 4; ++r) vb[(long)r * 1024] = o[r];
        }
      } else {
        float* cp = (float*)Cv + row * (long)ldc + col;
        if (col + 4 <= N) {
          f32x4 bv = *(const f32x4*)(bias + col);
          f32x4 o;
          #pragma unroll
          for (int r = 0; r < 4; ++r) o[r] = v[r] + bv[r];
          *(f32x4*)cp = o;
        } else {
          #pragma unroll
          for (int r = 0; r < 4; ++r)
            if (col + r < N) cp[r] = v[r] + bias[col + r];
        }
      }
    }
  }
}

// ---------------- 128x128 GEMM (QKV / FC / S-exp / PV / PROJ) ----------------
// MODE 0: bf16 = acc + bias (+ fused V-transpose scatter if vtp)   (QKV)
// MODE 1: bf16 = relu(acc + bias)                                   (FC)
// MODE 6: P = bf16(exp(acc*alpha)) causal-masked + rowsum atomics   (S-exp)
// MODE 7: f32 += acc / rowsum[row]                                  (PV)
// MODE 3: f32 += acc + bias                                         (PROJ)
#define BM 128
#define BN 128
#define BKK 32

template<int MODE>
__global__ __launch_bounds__(256) void gemm_kernel(
    const unsigned short* __restrict__ A, int lda,
    const unsigned short* __restrict__ B, int ldb,
    const float* __restrict__ bias,
    void* __restrict__ Cv, int ldc,
    int M, int N, int K,
    int NI, long sAo, long sAi, long sBo, long sBi,
    long sCo, long sCi, float alpha, int causal, int mblocks,
    float* __restrict__ rowsum, unsigned short* __restrict__ vtp) {
  __shared__ __align__(16) unsigned short As[2][BM * BKK];
  __shared__ __align__(16) unsigned short Bs[2][BN * BKK];
  int z = blockIdx.z;
  int zo = z / NI, zi = z - zo * NI;
  A += zo * sAo + zi * sAi;
  B += zo * sBo + zi * sBi;
  long coff = zo * sCo + zi * sCi;

  int m0, n0;
  if (mblocks > 0) {
    int bid = blockIdx.x;
    int mpx = mblocks >> 3;
    int xcd = bid & 7;
    int c = bid >> 3;
    m0 = (xcd * mpx + (c & (mpx - 1))) * BM;
    n0 = (c / mpx) * BN;
  } else {
    m0 = blockIdx.y * BM;
    n0 = blockIdx.x * BN;
  }
  if (causal == 1 && n0 > m0 + BM - 1) return;
  int kmax = (causal == 2) ? min(K, m0 + BM) : K;

  int tid = threadIdx.x;
  int lane = tid & 63;
  int wave = tid >> 6;
  int wm = (wave >> 1) * 64;
  int wn = (wave & 1) * 64;

  auto stage = [&](int buf, int k0) {
    #pragma unroll
    for (int i = 0; i < 2; ++i) {
      int c0 = i * 256 + wave * 64;
      int cc = c0 + lane;
      int row = cc >> 2;
      int ko = (cc & 3) << 3;
      GLDS(A + (long)(m0 + row) * lda + k0 + ko, As[buf] + c0 * 8);
      int rg = n0 + row; if (rg >= N) rg = N - 1;
      GLDS(B + (long)rg * ldb + k0 + ko, Bs[buf] + c0 * 8);
    }
  };

  f32x4 acc[4][4] = {};
  int nt = kmax / BKK;
  stage(0, 0);
  __syncthreads();
  int cur = 0;
  for (int t = 0; t < nt; ++t) {
    if (t + 1 < nt) stage(cur ^ 1, (t + 1) * BKK);
    int lr = lane & 15;
    int kg = (lane >> 4) << 3;
    i32x4 af[4], bf[4];
    #pragma unroll
    for (int mi = 0; mi < 4; ++mi)
      af[mi] = *(const i32x4*)(As[cur] + (wm + mi * 16 + lr) * BKK + kg);
    #pragma unroll
    for (int ni = 0; ni < 4; ++ni)
      bf[ni] = *(const i32x4*)(Bs[cur] + (wn + ni * 16 + lr) * BKK + kg);
    #pragma unroll
    for (int mi = 0; mi < 4; ++mi)
      #pragma unroll
      for (int ni = 0; ni < 4; ++ni)
        asm("v_mfma_f32_16x16x32_bf16 %0, %1, %2, %0"
            : "+v"(acc[mi][ni]) : "v"(bf[ni]), "v"(af[mi]));
    __syncthreads();
    cur ^= 1;
  }

  int cm = lane & 15;
  int cg = (lane >> 4) << 2;
  #pragma unroll
  for (int mi = 0; mi < 4; ++mi) {
    long row = m0 + wm + mi * 16 + cm;
    float rs = 0.f;
    #pragma unroll
    for (int ni = 0; ni < 4; ++ni) {
      int col = n0 + wn + ni * 16 + cg;
      f32x4 v = acc[mi][ni];
      if (MODE == 0 || MODE == 1) {           // N multiple of 128, no tail
        f32x4 bv = *(const f32x4*)(bias + col);
        u16x4 o;
        #pragma unroll
        for (int r = 0; r < 4; ++r) {
          float tt = v[r] + bv[r];
          if (MODE == 1) tt = fmaxf(tt, 0.f);
          o[r] = f2bf(tt);
        }
        *(u16x4*)((unsigned short*)Cv + coff + row * (long)ldc + col) = o;
        if (MODE == 0 && vtp && col >= 1536) {
          int vcol = col - 1536;
          int hh = vcol / 192;
          int dh = vcol - hh * 192;
          int bb = (int)(row >> 10);
          int tt2 = (int)(row & 1023);
          unsigned short* vb =
              vtp + ((long)(bb * 4 + hh) * 192 + dh) * 1024 + tt2;
          #pragma unroll
          for (int r = 0; r < 4; ++r) vb[(long)r * 1024] = o[r];
        }
      } else if (MODE == 6) {                 // exp-epilogue S->P (N=1024)
        u16x4 o;
        #pragma unroll
        for (int r = 0; r < 4; ++r) {
          float e = (col + r <= (int)row) ? __expf(v[r] * alpha) : 0.f;
          rs += e;
          o[r] = f2bf(e);
        }
        *(u16x4*)((unsigned short*)Cv + coff + row * (long)ldc + col) = o;
      } else if (MODE == 7) {                 // PV with fused normalize
        float inv = 1.0f / rowsum[(long)blockIdx.z * SEQ + row];
        float* cp = (float*)Cv + coff + row * (long)ldc + col;
        if (col + 4 <= N) {
          f32x4 old = *(f32x4*)cp;
          #pragma unroll
          for (int r = 0; r < 4; ++r) old[r] += v[r] * inv;
          *(f32x4*)cp = old;
        } else {
          #pragma unroll
          for (int r = 0; r < 4; ++r)
            if (col + r < N) cp[r] += v[r] * inv;
        }
      } else {                                // MODE 3 (PROJ)
        float* cp = (float*)Cv + coff + row * (long)ldc + col;
        if (col + 4 <= N) {
          f32x4 bv = bias ? *(const f32x4*)(bias + col)
                          : f32x4{0.f, 0.f, 0.f, 0.f};
          f32x4 old = *(f32x4*)cp;
          #pragma unroll
          for (int r = 0; r < 4; ++r) old[r] += v[r] + bv[r];
          *(f32x4*)cp = old;
        } else {
          #pragma unroll
          for (int r = 0; r < 4; ++r) {
            if (col + r < N) {
              float bvr = bias ? bias[col + r] : 0.f;
              cp[r] += v[r] + bvr;
            }
          }
        }
      }
    }
    if (MODE == 6)
      atomicAdd(rowsum + (long)blockIdx.z * SEQ + row, rs);
  }
}

extern "C" void kernel_launch(void* const* d_in, const int* in_sizes, int n_in,
                              void* d_out, int out_size, void* d_ws, size_t ws_size,
                              hipStream_t stream) {
  const int*   x       = (const int*)  d_in[0];
  const float* tok_emb = (const float*)d_in[1];
  const float* pos_emb = (const float*)d_in[2];
  const float* ln1_s   = (const float*)d_in[3];
  const float* ln1_b   = (const float*)d_in[4];
  const float* qkv_w   = (const float*)d_in[5];
  const float* qkv_b   = (const float*)d_in[6];
  const float* ln2_s   = (const float*)d_in[7];
  const float* ln2_b   = (const float*)d_in[8];
  const float* fc_w    = (const float*)d_in[9];
  const float* fc_b    = (const float*)d_in[10];
  const float* proj_w  = (const float*)d_in[11];
  const float* proj_b  = (const float*)d_in[12];
  const float* lnf_s   = (const float*)d_in[13];
  const float* lnf_b   = (const float*)d_in[14];
  const float* head_w  = (const float*)d_in[15];
  const float* head_b  = (const float*)d_in[16];

  char* ws = (char*)d_ws;
  size_t off = 0;
  auto alloc = [&](size_t bytes) {
    char* p = ws + off;
    off += (bytes + 255) & ~(size_t)255;
    return p;
  };
  float*          h   = (float*)         alloc((size_t)NTOK * D_MODEL * 4);
  unsigned short* lnb = (unsigned short*)alloc((size_t)NTOK * D_MODEL * 2);
  unsigned short* qkv = (unsigned short*)alloc((size_t)NTOK * 2304 * 2);
  unsigned short* vt  = (unsigned short*)alloc((size_t)16 * DHEAD * SEQ * 2);
  unsigned short* mid = (unsigned short*)alloc((size_t)NTOK * 3072 * 2);
  unsigned short* P   = (unsigned short*)alloc((size_t)16 * SEQ * SEQ * 2);
  float*          rsm = (float*)         alloc((size_t)NLAYER * 16 * SEQ * 4);
  unsigned short* wtq = (unsigned short*)alloc((size_t)2304 * 768 * 2);
  unsigned short* wtf = (unsigned short*)alloc((size_t)3072 * 768 * 2);
  unsigned short* wtp = (unsigned short*)alloc((size_t)768 * 3072 * 2);
  unsigned short* wth = (unsigned short*)alloc((size_t)50304 * 768 * 2);

  // zero all per-layer rowsum slices once (graph-safe async memset)
  hipMemsetAsync(rsm, 0, (size_t)NLAYER * 16 * SEQ * 4, stream);

  embed_kernel<<<NTOK, 256, 0, stream>>>(x, tok_emb, pos_emb, h);

  const float rscale = 0.07216878364870323f;  // 1/sqrt(192)

  for (int l = 0; l < NLAYER; ++l) {
    float* rowsum = rsm + (long)l * 16 * SEQ;
    // merged weight transposes + LN1 (one launch)
    wtln_kernel<<<6336 + NTOK, 256, 0, stream>>>(
        qkv_w + (long)l * 768 * 2304, fc_w + (long)l * 768 * 3072,
        proj_w + (long)l * 3072 * 768, wtq, wtf, wtp,
        h, ln1_s + l * 768, ln1_b + l * 768, lnb);
    // ---- attention ----
    // QKV on 128^2 kernel (576 blocks) with fused V-transpose
    gemm_kernel<0><<<576, 256, 0, stream>>>(
        lnb, 768, wtq, 768, qkv_b + l * 2304, qkv, 2304,
        4096, 2304, 768, 1, 0, 0, 0, 0, 0, 0, 1.0f, 0, 32, nullptr, vt);
    // P = exp(scale * Q K^T) masked, rowsum accumulated
    gemm_kernel<6><<<dim3(8, 8, 16), 256, 0, stream>>>(
        qkv, 2304, qkv + 768, 2304, nullptr, P, 1024,
        1024, 1024, 192, 4,
        (long)1024 * 2304, 192, (long)1024 * 2304, 192,
        (long)4 * 1024 * 1024, (long)1024 * 1024, rscale, 1, 0, rowsum, nullptr);
    // h += (P / rowsum) V
    gemm_kernel<7><<<dim3(2, 8, 16), 256, 0, stream>>>(
        P, 1024, vt, 1024, nullptr, h, 768,
        1024, 192, 1024, 4,
        (long)4 * 1024 * 1024, (long)1024 * 1024,
        (long)4 * 192 * 1024, (long)192 * 1024,
        (long)1024 * 768, 192, 1.0f, 2, 0, rowsum, nullptr);
    // ---- MLP ----
    ln_kernel<<<NTOK, 256, 0, stream>>>(h, ln2_s + l * 768, ln2_b + l * 768, lnb);
    // FC on 128^2 kernel (768 blocks)
    gemm_kernel<1><<<768, 256, 0, stream>>>(
        lnb, 768, wtf, 768, fc_b + l * 3072, mid, 3072,
        4096, 3072, 768, 1, 0, 0, 0, 0, 0, 0, 1.0f, 0, 32, nullptr, nullptr);
    // PROJ (R20-verified MODE 3, m-chunk-per-XCD swizzle)
    gemm_kernel<3><<<192, 256, 0, stream>>>(
        mid, 3072, wtp, 3072, proj_b + l * 768, h, 768,
        4096, 768, 3072, 1, 0, 0, 0, 0, 0, 0, 1.0f, 0, 32, nullptr, nullptr);
  }

  // ---- merged head weight transpose + final LN, then head GEMM ----
  wthln_kernel<<<1571 * 24 + NTOK, 256, 0, stream>>>(
      head_w, wth, h, lnf_s, lnf_b, lnb);
  gemm256_kernel<4><<<16 * 197, 512, 0, stream>>>(
      lnb, wth, head_b, (float*)d_out, 50257, 4096, 50257, 768, 16, nullptr);
}